// Round 3
// baseline (5280.387 us; speedup 1.0000x reference)
//
#include <hip/hip_runtime.h>
#include <math.h>

#define BB 4
#define TT 32
#define NN 1024
#define KK 16
#define HDIM 128
#define NO 512            // 4*HD gate rows
#define KG 132            // 4+HD contraction

// d_out offsets (floats)
#define OUT1_SZ ((size_t)BB*TT*132*NN)
#define OH (OUT1_SZ)
#define OC (OH + (size_t)BB*HDIM*NN)
#define OG (OC + (size_t)BB*HDIM*NN)

// ---------------------------------------------------------------------------
// Weight prep: transposed effective weights [k][512].
//   Layer0: gates = Wa0@pos_t + Wg0@[pp;h0] + b0,  Wa0 = w0[:,0:4]-w0[:,4:8]
//   Layer1: gates = Wa1@[pos_t;h0_t] + Wg1@[pp;h1] + b1
// ---------------------------------------------------------------------------
__global__ __launch_bounds__(256) void prep_weights(
    const float* __restrict__ w0, const float* __restrict__ w1,
    float* __restrict__ WaT0, float* __restrict__ WgT0,
    float* __restrict__ WaT1, float* __restrict__ WgT1)
{
  int idx = blockIdx.x * 256 + threadIdx.x;
  if (idx >= KG * NO) return;
  int k = idx / NO, o = idx - k * NO;
  WgT0[idx] = w0[o * 136 + 4 + k];
  WgT1[idx] = w1[o * 264 + 132 + k];
  float a1 = w1[o * 264 + k];
  if (k < 4) a1 -= w1[o * 264 + 132 + k];
  WaT1[idx] = a1;
  if (k < 4) WaT0[k * NO + o] = w0[o * 136 + k] - w0[o * 136 + 4 + k];
}

// ---------------------------------------------------------------------------
// KNN (verbatim from the round-1 PASSING kernel): per (b,t), exact top-16 by
// d2 = q2 + r2 - 2*qr with pinned rounding; sorted branch-insertion, ties ->
// lower index first (lax.top_k semantics).
// ---------------------------------------------------------------------------
__global__ __launch_bounds__(512) void knn_kernel(
    const float* __restrict__ x, int* __restrict__ gind, float* __restrict__ gfloat)
{
  __shared__ float rx[NN], ry[NN], rz[NN], rr[NN];
  int b = blockIdx.z, t = blockIdx.y;
  int tp = (t == 0) ? 0 : t - 1;
  const float* xr = x + (size_t)(b * TT + tp) * 4 * NN;
  for (int m = threadIdx.x; m < NN; m += 512) {
    float a = xr[m], e = xr[NN + m], c = xr[2 * NN + m];
    rx[m] = a; ry[m] = e; rz[m] = c;
    rr[m] = __fadd_rn(__fadd_rn(__fmul_rn(a, a), __fmul_rn(e, e)), __fmul_rn(c, c));
  }
  __syncthreads();
  int n = blockIdx.x * 512 + threadIdx.x;
  const float* xq = x + (size_t)(b * TT + t) * 4 * NN;
  float qx = xq[n], qy = xq[NN + n], qz = xq[2 * NN + n];
  float q2 = __fadd_rn(__fadd_rn(__fmul_rn(qx, qx), __fmul_rn(qy, qy)), __fmul_rn(qz, qz));
  float bd[KK]; int bi[KK];
#pragma unroll
  for (int i = 0; i < KK; ++i) { bd[i] = 3.402823466e38f; bi[i] = 0; }
  for (int m = 0; m < NN; ++m) {
    float s = __fmaf_rn(qz, rz[m], __fmaf_rn(qy, ry[m], __fmaf_rn(qx, rx[m], 0.0f)));
    float d2 = __fsub_rn(__fadd_rn(q2, rr[m]), __fmul_rn(2.0f, s));
    if (d2 < bd[KK - 1]) {
#pragma unroll
      for (int i = KK - 1; i > 0; --i) {
        float pv = bd[i - 1]; int pi = bi[i - 1];
        if (pv > d2)            { bd[i] = pv; bi[i] = pi; }
        else if (bd[i] > d2)    { bd[i] = d2; bi[i] = m; }
      }
      if (bd[0] > d2) { bd[0] = d2; bi[0] = m; }
    }
  }
  size_t base = ((size_t)(b * TT + t) * NN + n) * KK;
#pragma unroll
  for (int i = 0; i < KK; ++i) { gind[base + i] = bi[i]; gfloat[base + i] = (float)bi[i]; }
}

// ---------------------------------------------------------------------------
// No-LDS GEMM. Block = 4 waves; wave w owns 8 contiguous o-rows (wave-uniform
// => weights via scalar loads), lane owns 4 n-cols (float4 X loads from L2).
// Per thread: aG[8][4], aA[8][4]. Grid (4 nb, 16 ob, B).
//   G = WgT^T @ [pp_rows(4); hTg(128)]
//   A = WaT^T @ [pos_rows(4) (+ hTa(128) if KA==132)] + bias
// ---------------------------------------------------------------------------
template<int KA>
__global__ __launch_bounds__(256) void gemm_ag(
    const float* __restrict__ WgT, const float* __restrict__ WaT,
    const float* __restrict__ bias, const float* __restrict__ x,
    const float* __restrict__ hTg, size_t hTg_bstr,
    const float* __restrict__ hTa,
    int t, int tp,
    float* __restrict__ Aout, float* __restrict__ Gout)
{
  int tid = threadIdx.x;
  int w = tid >> 6, lane = tid & 63;
  int o0 = blockIdx.y * 32 + w * 8;
  int o0u = __builtin_amdgcn_readfirstlane(o0);
  int n0 = blockIdx.x * 256 + lane * 4;
  int b = blockIdx.z;

  float aG[8][4];
  float aA[8][4];
#pragma unroll
  for (int i = 0; i < 8; ++i)
#pragma unroll
    for (int j = 0; j < 4; ++j) { aG[i][j] = 0.0f; aA[i][j] = 0.0f; }

  const float* xg = x + (size_t)(b * TT + tp) * 4 * NN;   // pp frame
  const float* xa = x + (size_t)(b * TT + t) * 4 * NN;    // cur frame

  // position rows (k = 0..3)
#pragma unroll
  for (int k = 0; k < 4; ++k) {
    const float* wg = WgT + (size_t)k * NO + o0u;
    const float* wa = WaT + (size_t)k * NO + o0u;
    float4 vg4 = *(const float4*)(xg + (size_t)k * NN + n0);
    float4 va4 = *(const float4*)(xa + (size_t)k * NN + n0);
    float gv[4] = {vg4.x, vg4.y, vg4.z, vg4.w};
    float av[4] = {va4.x, va4.y, va4.z, va4.w};
#pragma unroll
    for (int i = 0; i < 8; ++i) {
      float wgi = wg[i], wai = wa[i];
#pragma unroll
      for (int j = 0; j < 4; ++j) {
        aG[i][j] = fmaf(wgi, gv[j], aG[i][j]);
        aA[i][j] = fmaf(wai, av[j], aA[i][j]);
      }
    }
  }

  // h rows (k = 4..131)
  const float* hg = hTg + (size_t)b * hTg_bstr + n0;
  const float* ha = hTa + (size_t)b * (HDIM * NN) + n0;
#pragma unroll 4
  for (int k = 0; k < HDIM; ++k) {
    const float* wg = WgT + (size_t)(4 + k) * NO + o0u;
    float4 vg4 = *(const float4*)(hg + (size_t)k * NN);
    float gv[4] = {vg4.x, vg4.y, vg4.z, vg4.w};
#pragma unroll
    for (int i = 0; i < 8; ++i) {
      float wgi = wg[i];
#pragma unroll
      for (int j = 0; j < 4; ++j) aG[i][j] = fmaf(wgi, gv[j], aG[i][j]);
    }
    if (KA == 132) {
      const float* wa = WaT + (size_t)(4 + k) * NO + o0u;
      float4 va4 = *(const float4*)(ha + (size_t)k * NN);
      float av[4] = {va4.x, va4.y, va4.z, va4.w};
#pragma unroll
      for (int i = 0; i < 8; ++i) {
        float wai = wa[i];
#pragma unroll
        for (int j = 0; j < 4; ++j) aA[i][j] = fmaf(wai, av[j], aA[i][j]);
      }
    }
  }

  const float* bv = bias + o0u;
  float b8[8];
#pragma unroll
  for (int i = 0; i < 8; ++i) b8[i] = bv[i];
#pragma unroll
  for (int j = 0; j < 4; ++j) {
    size_t row = ((size_t)b * NN + n0 + j) * NO + o0u;
    *(float4*)&Gout[row]     = make_float4(aG[0][j], aG[1][j], aG[2][j], aG[3][j]);
    *(float4*)&Gout[row + 4] = make_float4(aG[4][j], aG[5][j], aG[6][j], aG[7][j]);
    *(float4*)&Aout[row]     = make_float4(aA[0][j] + b8[0], aA[1][j] + b8[1],
                                           aA[2][j] + b8[2], aA[3][j] + b8[3]);
    *(float4*)&Aout[row + 4] = make_float4(aA[4][j] + b8[4], aA[5][j] + b8[5],
                                           aA[6][j] + b8[6], aA[7][j] + b8[7]);
  }
}

// ---------------------------------------------------------------------------
// Elementwise LSTM step: gather gates/cell at 16 neighbors, activations,
// max over k. Writes c (n-major, for next gather) and h^T (j-major, the GEMM
// operand / out1 slot).
// ---------------------------------------------------------------------------
__global__ __launch_bounds__(256) void ew_step(
    const float* __restrict__ A, const float* __restrict__ G,
    const int* __restrict__ gind,
    const float* __restrict__ c_in, float* __restrict__ c_out,
    float* __restrict__ hT, size_t hT_bstr, int t)
{
  int tid = threadIdx.x;
  int j = tid & 127, ns = tid >> 7;
  int b = blockIdx.y;
  int n = blockIdx.x * 2 + ns;
  const float* Ap = A + ((size_t)b * NN + n) * NO;
  float a0 = Ap[j], a1 = Ap[128 + j], a2 = Ap[256 + j], a3 = Ap[384 + j];
  const int* ip = gind + ((size_t)(b * TT + t) * NN + n) * KK;
  const float* Gb = G + (size_t)b * NN * NO;
  const float* cb = c_in + (size_t)b * NN * HDIM;
  float hmax = -3.402823466e38f, cmax = -3.402823466e38f;
#pragma unroll 4
  for (int k = 0; k < KK; ++k) {
    int m = ip[k];
    const float* Gp = Gb + (size_t)m * NO;
    float gi = a0 + Gp[j];
    float gf = a1 + Gp[128 + j];
    float go = a2 + Gp[256 + j];
    float gg = a3 + Gp[384 + j];
    float cg = cb[(size_t)m * HDIM + j];
    float si = 1.0f / (1.0f + __expf(-gi));
    float sf = 1.0f / (1.0f + __expf(-gf));
    float so = 1.0f / (1.0f + __expf(-go));
    float tg = 1.0f - 2.0f / (1.0f + __expf(2.0f * gg));
    float cn = sf * cg + si * tg;
    float tc = 1.0f - 2.0f / (1.0f + __expf(2.0f * cn));
    float hn = so * tc;
    hmax = fmaxf(hmax, hn);
    cmax = fmaxf(cmax, cn);
  }
  hT[(size_t)b * hT_bstr + (size_t)j * NN + n] = hmax;
  c_out[((size_t)b * NN + n) * HDIM + j] = cmax;
}

// Transpose (b,n,j)[N][128] -> dst[dstBase + b*bStride + j*N + n]  (for c out)
__global__ __launch_bounds__(256) void transpose_nj_jn(
    const float* __restrict__ src, float* __restrict__ dst,
    size_t dstBase, size_t bStride)
{
  __shared__ float tl[64][65];
  int tid = threadIdx.x;
  int n0 = blockIdx.x * 64, j0 = blockIdx.y * 64, b = blockIdx.z;
  int c = tid & 63, r4 = tid >> 6;
#pragma unroll
  for (int i = 0; i < 16; ++i) {
    int r = r4 + i * 4;
    tl[r][c] = src[((size_t)b * NN + n0 + r) * HDIM + j0 + c];
  }
  __syncthreads();
  float* dp = dst + dstBase + (size_t)b * bStride;
#pragma unroll
  for (int i = 0; i < 16; ++i) {
    int rr = r4 + i * 4;
    dp[(size_t)(j0 + rr) * NN + n0 + c] = tl[c][rr];
  }
}

// h output = copy of out1 slot at t=T-1 (already j-major)
__global__ __launch_bounds__(256) void copy_h(const float* __restrict__ out1,
                                              float* __restrict__ dst)
{
  int i = blockIdx.x * 256 + threadIdx.x;
  if (i >= BB * HDIM * NN) return;
  int b = i / (HDIM * NN);
  int r = i - b * (HDIM * NN);
  dst[i] = out1[((size_t)(b * TT + TT - 1) * 132 + 4) * NN + r];
}

// out1 position channels
__global__ __launch_bounds__(256) void pos_copy(const float* __restrict__ x,
                                                float* __restrict__ out)
{
  int i = blockIdx.x * 256 + threadIdx.x;
  if (i >= BB * TT * 4 * NN) return;
  int n = i & (NN - 1);
  int btc = i >> 10;
  int c = btc & 3, bt = btc >> 2;
  out[((size_t)bt * 132 + c) * NN + n] = x[i];
}

extern "C" void kernel_launch(void* const* d_in, const int* in_sizes, int n_in,
                              void* d_out, int out_size, void* d_ws, size_t ws_size,
                              hipStream_t stream)
{
  const float* x  = (const float*)d_in[0];
  const float* w0 = (const float*)d_in[1];
  const float* b0 = (const float*)d_in[2];
  const float* w1 = (const float*)d_in[3];
  const float* b1 = (const float*)d_in[4];
  float* out = (float*)d_out;

  float* wsf = (float*)d_ws;
  int*   gind = (int*)d_ws;
  size_t off = (size_t)BB * TT * NN * KK;          // gind ints
  const size_t HSZ = (size_t)BB * NN * HDIM;       // 524288
  float* h0T = wsf + off; off += HSZ;
  float* c0a = wsf + off; off += HSZ;
  float* c0b = wsf + off; off += HSZ;
  float* c1a = wsf + off; off += HSZ;
  float* c1b = wsf + off; off += HSZ;
  float* zeros = wsf + off; off += (size_t)HDIM * NN;
  float* Abuf = wsf + off; off += (size_t)BB * NN * NO;
  float* Gbuf = wsf + off; off += (size_t)BB * NN * NO;
  float* WaT0 = wsf + off; off += 4 * NO;
  float* WgT0 = wsf + off; off += (size_t)KG * NO;
  float* WaT1 = wsf + off; off += (size_t)KG * NO;
  float* WgT1 = wsf + off; off += (size_t)KG * NO;

  hipMemsetAsync(c0a, 0, HSZ * 4, stream);
  hipMemsetAsync(c1a, 0, HSZ * 4, stream);
  hipMemsetAsync(zeros, 0, (size_t)HDIM * NN * 4, stream);

  prep_weights<<<(KG * NO + 255) / 256, 256, 0, stream>>>(w0, w1, WaT0, WgT0, WaT1, WgT1);
  knn_kernel<<<dim3(2, TT, BB), 512, 0, stream>>>(x, gind, out + OG);
  pos_copy<<<(BB * TT * 4 * NN + 255) / 256, 256, 0, stream>>>(x, out);

  const size_t H_BSTR = (size_t)HDIM * NN;
  const size_t OUT_BSTR = (size_t)TT * 132 * NN;

  float* c0[2] = {c0a, c0b};
  float* c1[2] = {c1a, c1b};
  for (int t = 0; t < TT; ++t) {
    int tp = t ? t - 1 : 0;
    // ---- layer 0: G = Wg0@[pp; h0_{t-1}], A = Wa0@pos + b0
    const float* hTg0 = t ? h0T : zeros;
    gemm_ag<4><<<dim3(4, 16, BB), 256, 0, stream>>>(
        WgT0, WaT0, b0, x, hTg0, t ? H_BSTR : 0, h0T, t, tp, Abuf, Gbuf);
    ew_step<<<dim3(NN / 2, BB), 256, 0, stream>>>(
        Abuf, Gbuf, gind, c0[t & 1], c0[(t & 1) ^ 1], h0T, H_BSTR, t);
    // ---- layer 1: G = Wg1@[pp; h1_{t-1}], A = Wa1@[pos; h0_t] + b1
    const float* hTg1 = t ? (out + ((size_t)(t - 1) * 132 + 4) * NN) : zeros;
    gemm_ag<132><<<dim3(4, 16, BB), 256, 0, stream>>>(
        WgT1, WaT1, b1, x, hTg1, t ? OUT_BSTR : 0, h0T, t, tp, Abuf, Gbuf);
    ew_step<<<dim3(NN / 2, BB), 256, 0, stream>>>(
        Abuf, Gbuf, gind, c1[t & 1], c1[(t & 1) ^ 1],
        out + ((size_t)t * 132 + 4) * NN, OUT_BSTR, t);
  }
  // final h (copy of last out1 slot) and c (transpose)
  copy_h<<<(BB * HDIM * NN + 255) / 256, 256, 0, stream>>>(out, out + OH);
  transpose_nj_jn<<<dim3(16, 2, BB), 256, 0, stream>>>(c1[0], out, OC, (size_t)HDIM * NN);
}

// Round 5
// 3938.430 us; speedup vs baseline: 1.3407x; 1.3407x over previous
//
#include <hip/hip_runtime.h>
#include <math.h>

#define BB 4
#define TT 32
#define NN 1024
#define KK 16
#define HDIM 128
#define NO 512            // 4*HD gate rows
#define KG 132            // 4+HD contraction

// d_out offsets (floats)
#define OUT1_SZ ((size_t)BB*TT*132*NN)
#define OH (OUT1_SZ)
#define OC (OH + (size_t)BB*HDIM*NN)
#define OG (OC + (size_t)BB*HDIM*NN)

// ---------------------------------------------------------------------------
// Weight prep: transposed effective weights [k][512].
// ---------------------------------------------------------------------------
__global__ __launch_bounds__(256) void prep_weights(
    const float* __restrict__ w0, const float* __restrict__ w1,
    float* __restrict__ WaT0, float* __restrict__ WgT0,
    float* __restrict__ WaT1, float* __restrict__ WgT1)
{
  int idx = blockIdx.x * 256 + threadIdx.x;
  if (idx >= KG * NO) return;
  int k = idx / NO, o = idx - k * NO;
  WgT0[idx] = w0[o * 136 + 4 + k];
  WgT1[idx] = w1[o * 264 + 132 + k];
  float a1 = w1[o * 264 + k];
  if (k < 4) a1 -= w1[o * 264 + 132 + k];
  WaT1[idx] = a1;
  if (k < 4) WaT0[k * NO + o] = w0[o * 136 + k] - w0[o * 136 + 4 + k];
}

// ---------------------------------------------------------------------------
// KNN — VERBATIM the twice-proven R1 kernel. Do not modify (R2/R4 rewrites
// both failed group_ind with identical absmax; mechanism unexplained).
// ---------------------------------------------------------------------------
__global__ __launch_bounds__(512) void knn_kernel(
    const float* __restrict__ x, int* __restrict__ gind, float* __restrict__ gfloat)
{
  __shared__ float rx[NN], ry[NN], rz[NN], rr[NN];
  int b = blockIdx.z, t = blockIdx.y;
  int tp = (t == 0) ? 0 : t - 1;
  const float* xr = x + (size_t)(b * TT + tp) * 4 * NN;
  for (int m = threadIdx.x; m < NN; m += 512) {
    float a = xr[m], e = xr[NN + m], c = xr[2 * NN + m];
    rx[m] = a; ry[m] = e; rz[m] = c;
    rr[m] = __fadd_rn(__fadd_rn(__fmul_rn(a, a), __fmul_rn(e, e)), __fmul_rn(c, c));
  }
  __syncthreads();
  int n = blockIdx.x * 512 + threadIdx.x;
  const float* xq = x + (size_t)(b * TT + t) * 4 * NN;
  float qx = xq[n], qy = xq[NN + n], qz = xq[2 * NN + n];
  float q2 = __fadd_rn(__fadd_rn(__fmul_rn(qx, qx), __fmul_rn(qy, qy)), __fmul_rn(qz, qz));
  float bd[KK]; int bi[KK];
#pragma unroll
  for (int i = 0; i < KK; ++i) { bd[i] = 3.402823466e38f; bi[i] = 0; }
  for (int m = 0; m < NN; ++m) {
    float s = __fmaf_rn(qz, rz[m], __fmaf_rn(qy, ry[m], __fmaf_rn(qx, rx[m], 0.0f)));
    float d2 = __fsub_rn(__fadd_rn(q2, rr[m]), __fmul_rn(2.0f, s));
    if (d2 < bd[KK - 1]) {
#pragma unroll
      for (int i = KK - 1; i > 0; --i) {
        float pv = bd[i - 1]; int pi = bi[i - 1];
        if (pv > d2)            { bd[i] = pv; bi[i] = pi; }
        else if (bd[i] > d2)    { bd[i] = d2; bi[i] = m; }
      }
      if (bd[0] > d2) { bd[0] = d2; bi[0] = m; }
    }
  }
  size_t base = ((size_t)(b * TT + t) * NN + n) * KK;
#pragma unroll
  for (int i = 0; i < KK; ++i) { gind[base + i] = bi[i]; gfloat[base + i] = (float)bi[i]; }
}

// ---------------------------------------------------------------------------
// GEMM (R4-proven): block 256 = 4 waves; wave owns 4 o-rows (scalar weight
// loads), lane owns 1 n-col (4B coalesced X). Grid (16,32,B) = 8 waves/SIMD.
//   G = WgT^T @ [pp_rows(4); hTg(128)]
//   A = WaT^T @ [pos_rows(4) (+ hTa(128) if KA==132)] + bias
// ---------------------------------------------------------------------------
template<int KA>
__global__ __launch_bounds__(256) void gemm_ag(
    const float* __restrict__ WgT, const float* __restrict__ WaT,
    const float* __restrict__ bias, const float* __restrict__ x,
    const float* __restrict__ hTg, size_t hTg_bstr,
    const float* __restrict__ hTa,
    int t, int tp,
    float* __restrict__ Aout, float* __restrict__ Gout)
{
  int tid = threadIdx.x;
  int w = tid >> 6, lane = tid & 63;
  int o0u = __builtin_amdgcn_readfirstlane(blockIdx.y * 16 + w * 4);
  int n = blockIdx.x * 64 + lane;
  int b = blockIdx.z;

  float aG[4] = {0.f, 0.f, 0.f, 0.f};
  float aA[4] = {0.f, 0.f, 0.f, 0.f};

  const float* xg = x + (size_t)(b * TT + tp) * 4 * NN + n;  // pp frame
  const float* xa = x + (size_t)(b * TT + t) * 4 * NN + n;   // cur frame

#pragma unroll
  for (int k = 0; k < 4; ++k) {
    const float* wg = WgT + (size_t)k * NO + o0u;
    const float* wa = WaT + (size_t)k * NO + o0u;
    float gv = xg[(size_t)k * NN];
    float av = xa[(size_t)k * NN];
#pragma unroll
    for (int i = 0; i < 4; ++i) {
      aG[i] = fmaf(wg[i], gv, aG[i]);
      aA[i] = fmaf(wa[i], av, aA[i]);
    }
  }

  const float* hg = hTg + (size_t)b * hTg_bstr + n;
  const float* ha = hTa + (size_t)b * (HDIM * NN) + n;
#pragma unroll 4
  for (int k = 0; k < HDIM; ++k) {
    const float* wg = WgT + (size_t)(4 + k) * NO + o0u;
    float gv = hg[(size_t)k * NN];
#pragma unroll
    for (int i = 0; i < 4; ++i) aG[i] = fmaf(wg[i], gv, aG[i]);
    if (KA == 132) {
      const float* wa = WaT + (size_t)(4 + k) * NO + o0u;
      float av = ha[(size_t)k * NN];
#pragma unroll
      for (int i = 0; i < 4; ++i) aA[i] = fmaf(wa[i], av, aA[i]);
    }
  }

  const float* bv = bias + o0u;
  size_t row = ((size_t)b * NN + n) * NO + o0u;
  *(float4*)&Gout[row] = make_float4(aG[0], aG[1], aG[2], aG[3]);
  *(float4*)&Aout[row] = make_float4(aA[0] + bv[0], aA[1] + bv[1],
                                     aA[2] + bv[2], aA[3] + bv[3]);
}

// ---------------------------------------------------------------------------
// Elementwise LSTM step (R4-proven): block 1024 = 8 n x 128 j; j-coalesced
// gather reads, wave-uniform neighbor indices, padded-LDS transposed hT write.
// ---------------------------------------------------------------------------
__global__ __launch_bounds__(1024) void ew_step(
    const float* __restrict__ A, const float* __restrict__ G,
    const int* __restrict__ gind,
    const float* __restrict__ c_in, float* __restrict__ c_out,
    float* __restrict__ hT, size_t hT_bstr, int t)
{
  __shared__ float htile[HDIM][9];
  int tid = threadIdx.x;
  int j = tid & 127, ns = tid >> 7;     // ns 0..7
  int b = blockIdx.y;
  int n = blockIdx.x * 8 + ns;
  const float* Ap = A + ((size_t)b * NN + n) * NO;
  float a0 = Ap[j], a1 = Ap[128 + j], a2 = Ap[256 + j], a3 = Ap[384 + j];
  const int* ip = gind + ((size_t)(b * TT + t) * NN + n) * KK;
  const float* Gb = G + (size_t)b * NN * NO;
  const float* cb = c_in + (size_t)b * NN * HDIM;
  float hmax = -3.402823466e38f, cmax = -3.402823466e38f;
#pragma unroll 4
  for (int k = 0; k < KK; ++k) {
    int m = __builtin_amdgcn_readfirstlane(ip[k]);   // wave-uniform
    const float* Gp = Gb + (size_t)m * NO;
    float gi = a0 + Gp[j];
    float gf = a1 + Gp[128 + j];
    float go = a2 + Gp[256 + j];
    float gg = a3 + Gp[384 + j];
    float cg = cb[(size_t)m * HDIM + j];
    float si = 1.0f / (1.0f + __expf(-gi));
    float sf = 1.0f / (1.0f + __expf(-gf));
    float so = 1.0f / (1.0f + __expf(-go));
    float tg = 1.0f - 2.0f / (1.0f + __expf(2.0f * gg));
    float cn = sf * cg + si * tg;
    float tc = 1.0f - 2.0f / (1.0f + __expf(2.0f * cn));
    float hn = so * tc;
    hmax = fmaxf(hmax, hn);
    cmax = fmaxf(cmax, cn);
  }
  c_out[((size_t)b * NN + n) * HDIM + j] = cmax;
  htile[j][ns] = hmax;
  __syncthreads();
  int jw = tid >> 3, nn = tid & 7;
  hT[(size_t)b * hT_bstr + (size_t)jw * NN + blockIdx.x * 8 + nn] = htile[jw][nn];
}

// Transpose (b,n,j)[N][128] -> dst[dstBase + b*bStride + j*N + n]  (for c out)
__global__ __launch_bounds__(256) void transpose_nj_jn(
    const float* __restrict__ src, float* __restrict__ dst,
    size_t dstBase, size_t bStride)
{
  __shared__ float tl[64][65];
  int tid = threadIdx.x;
  int n0 = blockIdx.x * 64, j0 = blockIdx.y * 64, b = blockIdx.z;
  int c = tid & 63, r4 = tid >> 6;
#pragma unroll
  for (int i = 0; i < 16; ++i) {
    int r = r4 + i * 4;
    tl[r][c] = src[((size_t)b * NN + n0 + r) * HDIM + j0 + c];
  }
  __syncthreads();
  float* dp = dst + dstBase + (size_t)b * bStride;
#pragma unroll
  for (int i = 0; i < 16; ++i) {
    int rr = r4 + i * 4;
    dp[(size_t)(j0 + rr) * NN + n0 + c] = tl[c][rr];
  }
}

// h output = copy of out1 slot at t=T-1 (already j-major)
__global__ __launch_bounds__(256) void copy_h(const float* __restrict__ out1,
                                              float* __restrict__ dst)
{
  int i = blockIdx.x * 256 + threadIdx.x;
  if (i >= BB * HDIM * NN) return;
  int b = i / (HDIM * NN);
  int r = i - b * (HDIM * NN);
  dst[i] = out1[((size_t)(b * TT + TT - 1) * 132 + 4) * NN + r];
}

// out1 position channels
__global__ __launch_bounds__(256) void pos_copy(const float* __restrict__ x,
                                                float* __restrict__ out)
{
  int i = blockIdx.x * 256 + threadIdx.x;
  if (i >= BB * TT * 4 * NN) return;
  int n = i & (NN - 1);
  int btc = i >> 10;
  int c = btc & 3, bt = btc >> 2;
  out[((size_t)bt * 132 + c) * NN + n] = x[i];
}

extern "C" void kernel_launch(void* const* d_in, const int* in_sizes, int n_in,
                              void* d_out, int out_size, void* d_ws, size_t ws_size,
                              hipStream_t stream)
{
  const float* x  = (const float*)d_in[0];
  const float* w0 = (const float*)d_in[1];
  const float* b0 = (const float*)d_in[2];
  const float* w1 = (const float*)d_in[3];
  const float* b1 = (const float*)d_in[4];
  float* out = (float*)d_out;

  float* wsf = (float*)d_ws;
  int*   gind = (int*)d_ws;
  size_t off = (size_t)BB * TT * NN * KK;          // gind ints
  const size_t HSZ = (size_t)BB * NN * HDIM;       // 524288
  float* h0T = wsf + off; off += HSZ;
  float* c0a = wsf + off; off += HSZ;
  float* c0b = wsf + off; off += HSZ;
  float* c1a = wsf + off; off += HSZ;
  float* c1b = wsf + off; off += HSZ;
  float* zeros = wsf + off; off += (size_t)HDIM * NN;
  float* Abuf = wsf + off; off += (size_t)BB * NN * NO;
  float* Gbuf = wsf + off; off += (size_t)BB * NN * NO;
  float* WaT0 = wsf + off; off += 4 * NO;
  float* WgT0 = wsf + off; off += (size_t)KG * NO;
  float* WaT1 = wsf + off; off += (size_t)KG * NO;
  float* WgT1 = wsf + off; off += (size_t)KG * NO;

  hipMemsetAsync(c0a, 0, HSZ * 4, stream);
  hipMemsetAsync(c1a, 0, HSZ * 4, stream);
  hipMemsetAsync(zeros, 0, (size_t)HDIM * NN * 4, stream);

  prep_weights<<<(KG * NO + 255) / 256, 256, 0, stream>>>(w0, w1, WaT0, WgT0, WaT1, WgT1);
  knn_kernel<<<dim3(2, TT, BB), 512, 0, stream>>>(x, gind, out + OG);
  pos_copy<<<(BB * TT * 4 * NN + 255) / 256, 256, 0, stream>>>(x, out);

  const size_t H_BSTR = (size_t)HDIM * NN;
  const size_t OUT_BSTR = (size_t)TT * 132 * NN;

  float* c0[2] = {c0a, c0b};
  float* c1[2] = {c1a, c1b};
  for (int t = 0; t < TT; ++t) {
    int tp = t ? t - 1 : 0;
    // ---- layer 0: G = Wg0@[pp; h0_{t-1}], A = Wa0@pos + b0
    const float* hTg0 = t ? h0T : zeros;
    gemm_ag<4><<<dim3(16, 32, BB), 256, 0, stream>>>(
        WgT0, WaT0, b0, x, hTg0, t ? H_BSTR : 0, h0T, t, tp, Abuf, Gbuf);
    ew_step<<<dim3(NN / 8, BB), 1024, 0, stream>>>(
        Abuf, Gbuf, gind, c0[t & 1], c0[(t & 1) ^ 1], h0T, H_BSTR, t);
    // ---- layer 1: G = Wg1@[pp; h1_{t-1}], A = Wa1@[pos; h0_t] + b1
    const float* hTg1 = t ? (out + ((size_t)(t - 1) * 132 + 4) * NN) : zeros;
    gemm_ag<132><<<dim3(16, 32, BB), 256, 0, stream>>>(
        WgT1, WaT1, b1, x, hTg1, t ? OUT_BSTR : 0, h0T, t, tp, Abuf, Gbuf);
    ew_step<<<dim3(NN / 8, BB), 1024, 0, stream>>>(
        Abuf, Gbuf, gind, c1[t & 1], c1[(t & 1) ^ 1],
        out + ((size_t)t * 132 + 4) * NN, OUT_BSTR, t);
  }
  // final h (copy of last out1 slot) and c (transpose)
  copy_h<<<(BB * HDIM * NN + 255) / 256, 256, 0, stream>>>(out, out + OH);
  transpose_nj_jn<<<dim3(16, 2, BB), 256, 0, stream>>>(c1[0], out, OC, (size_t)HDIM * NN);
}